// Round 3
// baseline (273.215 us; speedup 1.0000x reference)
//
#include <hip/hip_runtime.h>

// Problem constants (fixed by reference):
//   N=16384 spatial, R=16 feat, P=4096 blocks, T=64 out-feat, B=8 batch
#define C_N 16384
#define C_R 16
#define C_P 4096
#define C_B 8

// One wave (= one 64-thread workgroup) per block p; grid 4096 -> 16 waves/CU
// resident. Lane = output column o. NO barriers anywhere: the wave stages its
// own 4 KB x-tile, then runs a double-buffered K-loop (chunks of 8 i-rows,
// 32 weight dword loads per chunk held in registers). Next chunk's loads are
// issued BEFORE the current chunk's first use, so the compiler's
// dependence-driven s_waitcnt is vmcnt(32) (keeps 32 loads in flight), not
// vmcnt(0) -- this is the in-flight depth R0/R1 lacked.
// VGPR budget: 64 (2x32 weight buf) + 16 acc + 16 x + addressing ~= 110;
// __launch_bounds__(64,4) caps at 128 -> 4 waves/SIMD = 16 waves/CU.
__global__ __launch_bounds__(64, 4)
void butterfly_local_conv(const float* __restrict__ x,
                          const float* __restrict__ Wrr,
                          const float* __restrict__ Wri,
                          const float* __restrict__ Wir,
                          const float* __restrict__ Wii,
                          const int*   __restrict__ perm,
                          float* __restrict__ out)
{
    __shared__ float xs[2][C_B][64];   // [c][b][i], i = s*16 + r   (4 KB)

    const int lane = threadIdx.x;      // 0..63 == output column o
    const int p    = blockIdx.x;

    // ---- stage permuted x: lane -> one (c,b,s) row of 16 floats.
    // Issue these 4 vmem loads FIRST (oldest in queue), then weight chunk 0,
    // so the ds_write's vmcnt wait leaves the weight loads in flight.
    const int sc = lane >> 5;          // 0..1  (re/im)
    const int sb = (lane >> 2) & 7;    // 0..7  (batch)
    const int ss = lane & 3;           // 0..3  (window position)
    const int n  = perm[4 * p + ss];
    const float4* xsrc = (const float4*)(x + (((size_t)(sb * 2 + sc)) * C_N + n) * C_R);
    const float4 v0 = xsrc[0], v1 = xsrc[1], v2 = xsrc[2], v3 = xsrc[3];

    // ---- weight base pointers (lane-indexed column)
    const size_t wbase = (size_t)p * 64 * 64 + lane;
    const float* __restrict__ prr = Wrr + wbase;
    const float* __restrict__ pri = Wri + wbase;
    const float* __restrict__ pir = Wir + wbase;
    const float* __restrict__ pii = Wii + wbase;

    // ---- prologue: chunk 0 into buf0
    float buf0[32], buf1[32];
    #pragma unroll
    for (int k = 0; k < 8; ++k) {
        buf0[k]      = prr[k * 64];
        buf0[8 + k]  = pri[k * 64];
        buf0[16 + k] = pir[k * 64];
        buf0[24 + k] = pii[k * 64];
    }

    // ---- now commit x to LDS (waits only the 4 x loads; weight loads stay
    // in flight). Same-wave visibility: no barrier needed.
    {
        float4* dst = (float4*)(&xs[sc][sb][ss * 16]);
        dst[0] = v0; dst[1] = v1; dst[2] = v2; dst[3] = v3;
    }

    float acc_re[C_B], acc_im[C_B];
    #pragma unroll
    for (int b = 0; b < C_B; ++b) { acc_re[b] = 0.0f; acc_im[b] = 0.0f; }

    // ---- main loop: 8 chunks of 8 i-rows, double-buffered
    #pragma unroll
    for (int ch = 0; ch < 8; ++ch) {
        float* cur = (ch & 1) ? buf1 : buf0;
        float* nxt = (ch & 1) ? buf0 : buf1;
        if (ch < 7) {
            const int ib = (ch + 1) * 8;
            #pragma unroll
            for (int k = 0; k < 8; ++k) {
                nxt[k]      = prr[(ib + k) * 64];
                nxt[8 + k]  = pri[(ib + k) * 64];
                nxt[16 + k] = pir[(ib + k) * 64];
                nxt[24 + k] = pii[(ib + k) * 64];
            }
        }
        const int i0 = ch * 8;
        #pragma unroll
        for (int b = 0; b < C_B; ++b) {
            float xr[8], xi[8];
            *(float4*)&xr[0] = *(const float4*)(&xs[0][b][i0]);
            *(float4*)&xr[4] = *(const float4*)(&xs[0][b][i0 + 4]);
            *(float4*)&xi[0] = *(const float4*)(&xs[1][b][i0]);
            *(float4*)&xi[4] = *(const float4*)(&xs[1][b][i0 + 4]);
            #pragma unroll
            for (int k = 0; k < 8; ++k) {
                acc_re[b] = fmaf(xr[k], cur[k],      acc_re[b]);
                acc_re[b] = fmaf(xi[k], cur[8 + k],  acc_re[b]);
                acc_im[b] = fmaf(xr[k], cur[16 + k], acc_im[b]);
                acc_im[b] = fmaf(xi[k], cur[24 + k], acc_im[b]);
            }
        }
    }

    // ---- epilogue: 16 coalesced 256 B stores
    const size_t obase = (size_t)p * 64 + lane;
    #pragma unroll
    for (int b = 0; b < C_B; ++b) {
        out[((size_t)(b * 2 + 0)) * (C_N * C_R) + obase] = acc_re[b];
        out[((size_t)(b * 2 + 1)) * (C_N * C_R) + obase] = acc_im[b];
    }
}

extern "C" void kernel_launch(void* const* d_in, const int* in_sizes, int n_in,
                              void* d_out, int out_size, void* d_ws, size_t ws_size,
                              hipStream_t stream) {
    const float* x    = (const float*)d_in[0];
    const float* Wrr  = (const float*)d_in[1];
    const float* Wri  = (const float*)d_in[2];
    const float* Wir  = (const float*)d_in[3];
    const float* Wii  = (const float*)d_in[4];
    const int*   perm = (const int*)d_in[5];
    float* out = (float*)d_out;

    // One single-wave WG per block p.
    butterfly_local_conv<<<dim3(C_P), dim3(64), 0, stream>>>(
        x, Wrr, Wri, Wir, Wii, perm, out);
}

// Round 4
// 261.550 us; speedup vs baseline: 1.0446x; 1.0446x over previous
//
#include <hip/hip_runtime.h>
#include <stdint.h>

// Problem constants (fixed by reference):
//   N=16384 spatial, R=16 feat, P=4096 blocks, T=64 out-feat, B=8 batch
#define C_N 16384
#define C_R 16
#define C_P 4096
#define C_B 8

// One 256-thread WG per (p, half): half=0 computes y_re from (Wrr,Wri),
// half=1 computes y_im from (Wir,Wii). Weights (32 KB) staged via async
// global_load_lds_dwordx4 (no VGPR destinations -> deep in-flight queue,
// which is the latency-hiding R1/R2 failed to get through registers).
// LDS = 32 KB weights + 4 KB x = 36 KB -> 4 WGs/CU resident, ~128 KB of
// weight DMA in flight per CU >> the ~9 KB needed to sustain 6.3 TB/s.
// One __syncthreads per WG; the vmcnt(0) drain is covered by the other
// resident WGs' transfers (kernel is purely memory-bound, 3.5 FLOP/B).
__global__ __launch_bounds__(256)
void butterfly_local_conv(const float* __restrict__ x,
                          const float* __restrict__ Wrr,
                          const float* __restrict__ Wri,
                          const float* __restrict__ Wir,
                          const float* __restrict__ Wii,
                          const int*   __restrict__ perm,
                          float* __restrict__ out)
{
    __shared__ float lw[2][64][64];   // 32 KB: [mat][i][o], exact row-major copy
    __shared__ float xs[2][C_B][64];  //  4 KB: [c][b][i], i = s*16 + r

    const int t    = threadIdx.x;
    const int lane = t & 63;
    const int w    = t >> 6;           // wave 0..3
    const int p    = blockIdx.x >> 1;
    const int half = blockIdx.x & 1;   // 0 -> y_re, 1 -> y_im

    const float* __restrict__ WA = half ? Wir : Wrr;
    const float* __restrict__ WB = half ? Wii : Wri;

    // ---- x tile: one float4 per thread (issue the global load now)
    const int sc = t >> 7;             // 0..1 (re/im component of x)
    const int sb = (t >> 4) & 7;       // 0..7 (batch)
    const int ss = (t >> 2) & 3;       // 0..3 (window position)
    const int sq = t & 3;              // float4 index within row of 16
    const int n  = perm[4 * p + ss];
    const float4 xv =
        ((const float4*)(x + (((size_t)(sb * 2 + sc)) * C_N + n) * C_R))[sq];

    // ---- async weight staging: wave w covers 8 KB (32 rows):
    //   w=0: WA rows 0..31, w=1: WA rows 32..63, w=2: WB rows 0..31, w=3: WB 32..63
    // Each instr: wave-uniform LDS base + lane*16B -> contiguous 1 KB (4 rows),
    // matching gptr = base + lane*16B. Row-major layout preserved exactly.
    {
        const float* Wsrc = (w < 2) ? WA : WB;
        const int    mat  = (w < 2) ? 0 : 1;
        const int    row0 = (w & 1) * 32;
        const float* gbase = Wsrc + (size_t)p * 4096 + (size_t)row0 * 64 + lane * 4;
        const float* lbase = &lw[mat][row0][0];
        #pragma unroll
        for (int j = 0; j < 8; ++j) {
            __builtin_amdgcn_global_load_lds(
                (const __attribute__((address_space(1))) uint32_t*)(gbase + j * 256),
                (__attribute__((address_space(3))) uint32_t*)((char*)lbase + j * 1024),
                16, 0, 0);
        }
    }

    // ---- commit x to LDS (waits only the x load; weight DMA stays queued)
    *(float4*)(&xs[sc][sb][ss * 16 + sq * 4]) = xv;

    __syncthreads();

    // ---- compute: lane = output column o; wave w handles batches 2w, 2w+1.
    // Weight ds_read: lanes read 64 consecutive dwords (2-way alias, free).
    // x ds_read: wave-uniform address -> broadcast, conflict-free.
    const int b0 = w * 2;
    float acc0 = 0.0f, acc1 = 0.0f;

    #pragma unroll
    for (int i0 = 0; i0 < 64; i0 += 8) {
        float wa[8], wb[8];
        #pragma unroll
        for (int k = 0; k < 8; ++k) {
            wa[k] = lw[0][i0 + k][lane];
            wb[k] = lw[1][i0 + k][lane];
        }
        float xr[8], xi[8];
        *(float4*)&xr[0] = *(const float4*)(&xs[0][b0][i0]);
        *(float4*)&xr[4] = *(const float4*)(&xs[0][b0][i0 + 4]);
        *(float4*)&xi[0] = *(const float4*)(&xs[1][b0][i0]);
        *(float4*)&xi[4] = *(const float4*)(&xs[1][b0][i0 + 4]);
        #pragma unroll
        for (int k = 0; k < 8; ++k) {
            acc0 = fmaf(xr[k], wa[k], acc0);
            acc0 = fmaf(xi[k], wb[k], acc0);
        }
        *(float4*)&xr[0] = *(const float4*)(&xs[0][b0 + 1][i0]);
        *(float4*)&xr[4] = *(const float4*)(&xs[0][b0 + 1][i0 + 4]);
        *(float4*)&xi[0] = *(const float4*)(&xs[1][b0 + 1][i0]);
        *(float4*)&xi[4] = *(const float4*)(&xs[1][b0 + 1][i0 + 4]);
        #pragma unroll
        for (int k = 0; k < 8; ++k) {
            acc1 = fmaf(xr[k], wa[k], acc1);
            acc1 = fmaf(xi[k], wb[k], acc1);
        }
    }

    // ---- store: 2 coalesced 256 B stores per wave
    const size_t obase = (size_t)p * 64 + lane;
    out[((size_t)(b0 * 2 + half)) * (C_N * C_R) + obase] = acc0;
    out[((size_t)((b0 + 1) * 2 + half)) * (C_N * C_R) + obase] = acc1;
}

extern "C" void kernel_launch(void* const* d_in, const int* in_sizes, int n_in,
                              void* d_out, int out_size, void* d_ws, size_t ws_size,
                              hipStream_t stream) {
    const float* x    = (const float*)d_in[0];
    const float* Wrr  = (const float*)d_in[1];
    const float* Wri  = (const float*)d_in[2];
    const float* Wir  = (const float*)d_in[3];
    const float* Wii  = (const float*)d_in[4];
    const int*   perm = (const int*)d_in[5];
    float* out = (float*)d_out;

    // 2 WGs per block p (re half, im half): grid 8192 x 256 threads.
    butterfly_local_conv<<<dim3(C_P * 2), dim3(256), 0, stream>>>(
        x, Wrr, Wri, Wir, Wii, perm, out);
}